// Round 8
// baseline (169.855 us; speedup 1.0000x reference)
//
#include <hip/hip_runtime.h>
#include <hip/hip_bf16.h>

// GAT layer: B=8, N=8 (BN=64 batches), Nodes=512, IF=OF=256.
// MFMA on v_mfma_f32_16x16x32_bf16, split-bf16 (hi+lo) operands.
//
// Key structure (r8): NO LDS staging for B operands (each B byte is used by
// exactly one wave -> staging buys nothing; Wt/WhT are L2-resident). B-frags
// are loaded per-lane straight to VGPRs (16B/lane, each wave op = 16 full
// 64B lines). Only the shared A panel lives in LDS (swizzled, built once).
// K-loops are completely barrier-free.
//
//  K0: detect dtype -> flag
//  KP: W -> Wt[f][k] bf16 hi/lo
//  KA: Wh = h@W. 512 blocks x 256 thr. A(h) panel (64x256, hi/lo) staged to
//      LDS once; 8-step barrier-free K-loop with direct-global B.
//  KB: fused softmax (P pre-normalized bf16 in LDS) + out=elu(P@Wh).
//      512 blocks x 512 thr, launch_bounds(512,4) -> 2 blocks/CU, 16 waves/CU.
//      16-step barrier-free K-loop with direct-global B. XCD-swizzled.

#define ALPHA 0.2f
#define MASK_VAL -9000000000000000.0f
#define NODES 512
#define FDIM 256
#define BN 64

typedef float  f32x4 __attribute__((ext_vector_type(4)));
typedef int    i32x4 __attribute__((ext_vector_type(4)));
typedef short  s16x8 __attribute__((ext_vector_type(8)));
typedef short  s16x4 __attribute__((ext_vector_type(4)));
typedef __bf16 bf16x8 __attribute__((ext_vector_type(8)));

__device__ __forceinline__ unsigned short f2bfu(float x) {
    __hip_bfloat16 b = __float2bfloat16(x);   // RNE
    unsigned short u; __builtin_memcpy(&u, &b, 2); return u;
}
__device__ __forceinline__ float bfu2f(unsigned short u) {
    unsigned int w = ((unsigned int)u) << 16; return __uint_as_float(w);
}
__device__ __forceinline__ f32x4 mfma16(s16x8 a, s16x8 b, f32x4 c) {
    return __builtin_amdgcn_mfma_f32_16x16x32_bf16(
        __builtin_bit_cast(bf16x8, a), __builtin_bit_cast(bf16x8, b), c, 0, 0, 0);
}

// hi/lo split of 8 fp32 (truncation split; residual ~2^-16 rel).
__device__ __forceinline__ void split8v(f32x4 v0, f32x4 v1, s16x8& hi, s16x8& lo)
{
    float x[8] = {v0[0], v0[1], v0[2], v0[3], v1[0], v1[1], v1[2], v1[3]};
    unsigned hw[4], lw[4];
    #pragma unroll
    for (int d = 0; d < 4; ++d) {
        const unsigned u0 = __float_as_uint(x[2*d]);
        const unsigned u1 = __float_as_uint(x[2*d + 1]);
        hw[d] = __builtin_amdgcn_perm(u1, u0, 0x07060302);
        const float l0 = x[2*d]     - __uint_as_float(u0 & 0xFFFF0000u);
        const float l1 = x[2*d + 1] - __uint_as_float(u1 & 0xFFFF0000u);
        lw[d] = __builtin_amdgcn_perm(__float_as_uint(l1), __float_as_uint(l0),
                                      0x07060302);
    }
    hi = __builtin_bit_cast(s16x8, *(unsigned(*)[4])hw);
    lo = __builtin_bit_cast(s16x8, *(unsigned(*)[4])lw);
}

__device__ __forceinline__ void gll16(const void* g, void* l) {
    __builtin_amdgcn_global_load_lds(
        (const __attribute__((address_space(1))) unsigned int*)g,
        (__attribute__((address_space(3))) unsigned int*)l,
        16, 0, 0);
}

// ---------------- K0: dtype detect ----------------
__global__ __launch_bounds__(256) void detect_kernel(const unsigned short* __restrict__ hraw,
                                                     int* __restrict__ flag)
{
    const int tid = threadIdx.x;
    float m = 0.0f;
    for (int i = tid; i < 16384; i += 256) {
        unsigned int w = ((unsigned int)hraw[i]) << 16;
        float v = __uint_as_float(w);
        v = fabsf(v);
        if (!(v == v)) v = 1e30f;
        m = fmaxf(m, v);
    }
    #pragma unroll
    for (int off = 32; off >= 1; off >>= 1)
        m = fmaxf(m, __shfl_down(m, off));
    __shared__ float red[4];
    if ((tid & 63) == 0) red[tid >> 6] = m;
    __syncthreads();
    if (tid == 0) {
        float mm = fmaxf(fmaxf(red[0], red[1]), fmaxf(red[2], red[3]));
        *flag = (mm > 1e4f) ? 1 : 0;
    }
}

// ---------------- KP: W -> Wt[f][k] bf16 hi/lo ----------------
__global__ __launch_bounds__(256) void prep_w_kernel(
    const void* __restrict__ Wv, const int* __restrict__ flagp,
    short* __restrict__ WtHi, short* __restrict__ WtLo)
{
    const int flag = *flagp;
    __shared__ float tile[16][17];
    const int tx = threadIdx.x & 15, ty = threadIdx.x >> 4;
    const int kk = blockIdx.y * 16 + ty;
    const int f  = blockIdx.x * 16 + tx;
    float v;
    if (flag) v = ((const float*)Wv)[kk * FDIM + f];
    else      v = bfu2f(((const unsigned short*)Wv)[kk * FDIM + f]);
    tile[ty][tx] = v;
    __syncthreads();
    const float x = tile[tx][ty];
    const int fo = blockIdx.x * 16 + ty;
    const int ko = blockIdx.y * 16 + tx;
    unsigned short h = f2bfu(x);
    WtHi[fo * FDIM + ko] = (short)h;
    WtLo[fo * FDIM + ko] = (short)f2bfu(x - bfu2f(h));  // exact 0 in bf16 mode
}

// ---------------- KA: Wh = h@W ----------------
// 512 blocks x 256 thr (4 waves). A panel (64 rows x 256 k) in LDS,
// hi at [0,32K), lo at [32K,64K); byte = row*512 + ((seg ^ (row&7))*16),
// seg = k/8.  K-loop: barrier-free, B-fragments direct from global (L2).
__global__ __launch_bounds__(256, 2) void wh_gemm(
    const void* __restrict__ hv,
    const short* __restrict__ WtHi, const short* __restrict__ WtLo,
    const void* __restrict__ av, const int* __restrict__ flagp,
    short* __restrict__ WhTHi, short* __restrict__ WhTLo,
    float* __restrict__ srcv, float* __restrict__ dstv)
{
    __shared__ __align__(16) char smem[67584];   // A hi 32K | A lo 32K | red 2K

    const int flag = *flagp;
    const int blk = blockIdx.x;
    const int bn  = blk >> 3;
    const int i0  = (blk & 7) * 64;
    const size_t r0g = (size_t)blk * 64;
    const int tid = threadIdx.x;
    const int w = tid >> 6, l = tid & 63;
    const int fb = l & 15, g = l >> 4;

    // ---- stage A panel once ----
    if (flag) {
        const int srow = tid >> 2, q = tid & 3;
        const float* gA = (const float*)hv + (r0g + srow) * FDIM;
        #pragma unroll
        for (int i = 0; i < 8; ++i) {
            const int seg = q + 4 * i;            // coalesced across q
            f32x4 v0 = *(const f32x4*)(gA + seg * 8);
            f32x4 v1 = *(const f32x4*)(gA + seg * 8 + 4);
            s16x8 hi, lo; split8v(v0, v1, hi, lo);
            const int slot = seg ^ (srow & 7);
            *(s16x8*)(smem + srow * 512 + slot * 16) = hi;
            *(s16x8*)(smem + 32768 + srow * 512 + slot * 16) = lo;
        }
    } else {
        const short* hs = (const short*)hv;
        const unsigned wub = (unsigned)(tid & ~63);
        #pragma unroll
        for (int i = 0; i < 8; ++i) {
            const int idx = i * 256 + tid;        // 0..2047
            const int row = idx >> 5, slot = idx & 31;
            const int srcseg = slot ^ (row & 7);
            gll16(hs + (r0g + row) * FDIM + srcseg * 8,
                  smem + (i * 256 + (int)wub) * 16);
        }
    }
    __syncthreads();   // drains vmcnt+lgkm; A panel ready

    f32x4 acc[4][4];
    #pragma unroll
    for (int rt = 0; rt < 4; ++rt)
        #pragma unroll
        for (int ct = 0; ct < 4; ++ct) acc[rt][ct] = f32x4{0.f,0.f,0.f,0.f};

    // ---- barrier-free K-loop (8 steps), B direct from global ----
    if (flag) {
        #pragma unroll
        for (int t = 0; t < 8; ++t) {
            s16x8 bh[4], bl[4], ah[4], al[4];
            #pragma unroll
            for (int ct = 0; ct < 4; ++ct) {
                const int f = w * 64 + ct * 16 + fb;
                bh[ct] = *(const s16x8*)(WtHi + f * FDIM + t * 32 + g * 8);
                bl[ct] = *(const s16x8*)(WtLo + f * FDIM + t * 32 + g * 8);
            }
            #pragma unroll
            for (int rt = 0; rt < 4; ++rt) {
                const int row = rt * 16 + fb;
                const int slot = (t * 4 + g) ^ (row & 7);
                ah[rt] = *(const s16x8*)(smem + row * 512 + slot * 16);
                al[rt] = *(const s16x8*)(smem + 32768 + row * 512 + slot * 16);
            }
            #pragma unroll
            for (int rt = 0; rt < 4; ++rt)
                #pragma unroll
                for (int ct = 0; ct < 4; ++ct) {
                    acc[rt][ct] = mfma16(ah[rt], bh[ct], acc[rt][ct]);
                    acc[rt][ct] = mfma16(al[rt], bh[ct], acc[rt][ct]);
                    acc[rt][ct] = mfma16(ah[rt], bl[ct], acc[rt][ct]);
                }
        }
    } else {
        #pragma unroll
        for (int t = 0; t < 8; ++t) {
            s16x8 bh[4], ah[4];
            #pragma unroll
            for (int ct = 0; ct < 4; ++ct) {
                const int f = w * 64 + ct * 16 + fb;
                bh[ct] = *(const s16x8*)(WtHi + f * FDIM + t * 32 + g * 8);
            }
            #pragma unroll
            for (int rt = 0; rt < 4; ++rt) {
                const int row = rt * 16 + fb;
                const int slot = (t * 4 + g) ^ (row & 7);
                ah[rt] = *(const s16x8*)(smem + row * 512 + slot * 16);
            }
            #pragma unroll
            for (int rt = 0; rt < 4; ++rt)
                #pragma unroll
                for (int ct = 0; ct < 4; ++ct)
                    acc[rt][ct] = mfma16(ah[rt], bh[ct], acc[rt][ct]);
        }
    }

    // Write WhT[bn][f][i] hi/lo. D: row = rt*16 + g*4 + r, col = f.
    const size_t wbT = (size_t)bn * FDIM * NODES;
    #pragma unroll
    for (int rt = 0; rt < 4; ++rt) {
        const int orow = i0 + rt * 16 + g * 4;
        #pragma unroll
        for (int ct = 0; ct < 4; ++ct) {
            const int f = w * 64 + ct * 16 + fb;
            s16x4 h4, l4;
            #pragma unroll
            for (int r = 0; r < 4; ++r) {
                float x = acc[rt][ct][r];
                unsigned short hh = f2bfu(x);
                h4[r] = (short)hh;
                l4[r] = (short)f2bfu(x - bfu2f(hh));
            }
            *(s16x4*)(WhTHi + wbT + (size_t)f * NODES + orow) = h4;
            *(s16x4*)(WhTLo + wbT + (size_t)f * NODES + orow) = l4;
        }
    }

    // src/dst reduction (fp32 accumulator path).
    float a1v[4], a2v[4];
    #pragma unroll
    for (int ct = 0; ct < 4; ++ct) {
        const int f = w * 64 + ct * 16 + fb;
        if (flag) {
            a1v[ct] = ((const float*)av)[f];
            a2v[ct] = ((const float*)av)[FDIM + f];
        } else {
            a1v[ct] = bfu2f(((const unsigned short*)av)[f]);
            a2v[ct] = bfu2f(((const unsigned short*)av)[FDIM + f]);
        }
    }
    float* red1 = (float*)(smem + 65536);   // [4][64]
    float* red2 = red1 + 256;
    #pragma unroll
    for (int rt = 0; rt < 4; ++rt) {
        #pragma unroll
        for (int r = 0; r < 4; ++r) {
            float s1 = 0.f, s2 = 0.f;
            #pragma unroll
            for (int ct = 0; ct < 4; ++ct) {
                s1 = fmaf(acc[rt][ct][r], a1v[ct], s1);
                s2 = fmaf(acc[rt][ct][r], a2v[ct], s2);
            }
            #pragma unroll
            for (int off = 1; off <= 8; off <<= 1) {
                s1 += __shfl_xor(s1, off);
                s2 += __shfl_xor(s2, off);
            }
            if (fb == 0) {
                red1[w * 64 + rt * 16 + g * 4 + r] = s1;
                red2[w * 64 + rt * 16 + g * 4 + r] = s2;
            }
        }
    }
    __syncthreads();
    if (tid < 64) {
        srcv[bn * NODES + i0 + tid] =
            red1[tid] + red1[64 + tid] + red1[128 + tid] + red1[192 + tid];
        dstv[bn * NODES + i0 + tid] =
            red2[tid] + red2[64 + tid] + red2[128 + tid] + red2[192 + tid];
    }
}

// ---------------- KB: fused softmax + att@Wh + elu ----------------
// 512 blocks (XCD-swizzled) x 512 thr (8 waves), launch_bounds(512,4):
// VGPR<=128, LDS 64.25K -> 2 blocks/CU (16 waves/CU). Wave w owns cols
// [w*32,w*32+32). P (pre-normalized bf16) in LDS; K-loop barrier-free,
// B-fragments direct from global (WhT is per-XCD L2-resident).
__global__ __launch_bounds__(512, 4) void pv_gemm(
    const short* __restrict__ WhTHi, const short* __restrict__ WhTLo,
    const float* __restrict__ srcv, const float* __restrict__ dstv,
    const int* __restrict__ adj, const int* __restrict__ flagp,
    void* __restrict__ out)
{
    __shared__ __align__(16) char smem[65792];   // Ps 64K | rowinv 256B

    const int flag = *flagp;
    const int b0 = blockIdx.x;
    const int blk = (b0 & 7) * 64 + (b0 >> 3);   // bijective: 512 % 8 == 0
    const int bn  = blk >> 3;
    const int i0  = (blk & 7) * 64;
    const int tid = threadIdx.x;
    const int w = tid >> 6, l = tid & 63;

    const short* bhig = WhTHi + (size_t)bn * FDIM * NODES;
    const short* blog = WhTLo + (size_t)bn * FDIM * NODES;
    float* rowinvS = (float*)(smem + 65536);

    // ---- softmax: wave w -> rows w*8..w*8+8; lane l covers j = 8l..8l+8 ----
    {
        const float* drow = dstv + bn * NODES;
        const int j = l * 8;
        for (int rr = 0; rr < 8; ++rr) {
            const int r = w * 8 + rr;
            const int* adjrow = adj + (size_t)(i0 + r) * NODES;
            const float srow = srcv[bn * NODES + i0 + r];
            const i32x4 q0 = *(const i32x4*)(adjrow + j);
            const i32x4 q1 = *(const i32x4*)(adjrow + j + 4);
            const f32x4 d0 = *(const f32x4*)(drow + j);
            const f32x4 d1 = *(const f32x4*)(drow + j + 4);
            float e[8];
            #pragma unroll
            for (int k = 0; k < 4; ++k) {
                float ev = srow + d0[k];
                ev = (ev > 0.f) ? ev : ALPHA * ev;
                e[k] = (q0[k] > 0) ? ev : MASK_VAL;
                float ew = srow + d1[k];
                ew = (ew > 0.f) ? ew : ALPHA * ew;
                e[4 + k] = (q1[k] > 0) ? ew : MASK_VAL;
            }
            float m = e[0];
            #pragma unroll
            for (int k = 1; k < 8; ++k) m = fmaxf(m, e[k]);
            #pragma unroll
            for (int off = 1; off <= 32; off <<= 1) m = fmaxf(m, __shfl_xor(m, off));
            float p[8], s = 0.f;
            #pragma unroll
            for (int k = 0; k < 8; ++k) {
                p[k] = __expf(e[k] - m);   // masked -> 0; all-masked row -> 1
                s += p[k];
            }
            #pragma unroll
            for (int off = 1; off <= 32; off <<= 1) s += __shfl_xor(s, off);
            const float isum = 1.0f / s;
            s16x8 ph;
            #pragma unroll
            for (int k = 0; k < 8; ++k) ph[k] = (short)f2bfu(p[k] * isum);
            // chunk l stored at slot l ^ (r&7)
            *(s16x8*)(smem + r * 1024 + ((l ^ (r & 7)) * 16)) = ph;
            if (l == 0) rowinvS[r] = isum;   // kept for debug parity (unused)
        }
    }
    __syncthreads();   // P ready for all waves

    // ---- PV GEMM: 16 K-steps, barrier-free, B direct from global ----
    const int fb = l & 15, g = l >> 4;
    const int f0 = w * 32 + fb;          // ct=0 col
    const int f1 = f0 + 16;              // ct=1 col
    const short* gH0 = bhig + (size_t)f0 * NODES + g * 8;
    const short* gH1 = bhig + (size_t)f1 * NODES + g * 8;
    const short* gL0 = blog + (size_t)f0 * NODES + g * 8;
    const short* gL1 = blog + (size_t)f1 * NODES + g * 8;

    f32x4 acc[4][2];
    #pragma unroll
    for (int rt = 0; rt < 4; ++rt)
        #pragma unroll
        for (int ct = 0; ct < 2; ++ct) acc[rt][ct] = f32x4{0.f,0.f,0.f,0.f};

    #pragma unroll 4
    for (int t = 0; t < 16; ++t) {
        s16x8 bh0 = *(const s16x8*)(gH0 + t * 32);
        s16x8 bh1 = *(const s16x8*)(gH1 + t * 32);
        s16x8 bl0 = *(const s16x8*)(gL0 + t * 32);
        s16x8 bl1 = *(const s16x8*)(gL1 + t * 32);
        s16x8 af[4];
        #pragma unroll
        for (int rt = 0; rt < 4; ++rt) {
            const int row = rt * 16 + fb;
            const unsigned seg = (unsigned)(t * 4 + g) ^ (unsigned)(row & 7);
            af[rt] = *(const s16x8*)(smem + (unsigned)(row * 1024) + seg * 16);
        }
        #pragma unroll
        for (int rt = 0; rt < 4; ++rt) {
            acc[rt][0] = mfma16(af[rt], bh0, acc[rt][0]);
            acc[rt][0] = mfma16(af[rt], bl0, acc[rt][0]);
            acc[rt][1] = mfma16(af[rt], bh1, acc[rt][1]);
            acc[rt][1] = mfma16(af[rt], bl1, acc[rt][1]);
        }
    }

    // epilogue: elu, store (P pre-normalized). D row = rt*16 + g*4 + r.
    #pragma unroll
    for (int rt = 0; rt < 4; ++rt) {
        #pragma unroll
        for (int ct = 0; ct < 2; ++ct) {
            const int f = w * 32 + ct * 16 + fb;
            #pragma unroll
            for (int r = 0; r < 4; ++r) {
                float v = acc[rt][ct][r];
                v = (v > 0.f) ? v : expm1f(v);
                const size_t o = ((size_t)bn * NODES + i0 + rt * 16 + g * 4 + r) * FDIM + f;
                if (flag) ((float*)out)[o] = v;
                else      ((unsigned short*)out)[o] = f2bfu(v);
            }
        }
    }
}

extern "C" void kernel_launch(void* const* d_in, const int* in_sizes, int n_in,
                              void* d_out, int out_size, void* d_ws, size_t ws_size,
                              hipStream_t stream)
{
    const void* h   = d_in[0];
    const int*  adj = (const int*)d_in[1];
    const void* W   = d_in[2];
    const void* a   = d_in[3];

    // ws layout: flag 256B | src 128K | dst 128K | WtHi 128K | WtLo 128K
    //            | WhTHi 16.78M | WhTLo 16.78M   (~34.1 MB total)
    int*   flag  = (int*)d_ws;
    float* srcv  = (float*)d_ws + 64;
    float* dstv  = srcv + BN * NODES;
    short* WtHi  = (short*)(dstv + BN * NODES);
    short* WtLo  = WtHi + FDIM * FDIM;
    short* WhTHi = WtLo + FDIM * FDIM;
    short* WhTLo = WhTHi + (size_t)BN * FDIM * NODES;

    detect_kernel<<<1, 256, 0, stream>>>((const unsigned short*)h, flag);
    prep_w_kernel<<<dim3(16, 16), 256, 0, stream>>>(W, flag, WtHi, WtLo);
    wh_gemm<<<512, 256, 0, stream>>>(h, WtHi, WtLo, a, flag,
                                     WhTHi, WhTLo, srcv, dstv);
    pv_gemm<<<512, 512, 0, stream>>>(WhTHi, WhTLo, srcv, dstv, adj, flag, d_out);
}

// Round 9
// 167.390 us; speedup vs baseline: 1.0147x; 1.0147x over previous
//
#include <hip/hip_runtime.h>
#include <hip/hip_bf16.h>

// GAT layer: B=8, N=8 (BN=64 batches), Nodes=512, IF=OF=256.
// MFMA on v_mfma_f32_16x16x32_bf16, split-bf16 (hi+lo) operands.
//
// r9 structure: B operands loaded per-lane direct from global (L2-resident;
// no LDS staging), but with an EXPLICIT depth-2 register pipeline (pb[3][.]
// rotation, fully unrolled -> static indices) so ~8 loads stay in flight per
// wave (~300cy load-to-use distance ~ L2 latency). A panels in swizzled LDS.
//
//  K0: detect dtype -> flag
//  KP: W -> Wt[f][k] bf16 hi/lo
//  KA: Wh = h@W. 512 blocks x 512 thr (8 waves, 2 blocks/CU, 16 waves/CU).
//      A(h) panel staged once; barrier-free pipelined K-loop.
//  KB: fused softmax (P pre-normalized bf16 in LDS) + out=elu(P@Wh).
//      512 blocks x 512 thr, barrier-free pipelined K-loop. XCD-swizzled.

#define ALPHA 0.2f
#define MASK_VAL -9000000000000000.0f
#define NODES 512
#define FDIM 256
#define BN 64

typedef float  f32x4 __attribute__((ext_vector_type(4)));
typedef int    i32x4 __attribute__((ext_vector_type(4)));
typedef short  s16x8 __attribute__((ext_vector_type(8)));
typedef short  s16x4 __attribute__((ext_vector_type(4)));
typedef __bf16 bf16x8 __attribute__((ext_vector_type(8)));

__device__ __forceinline__ unsigned short f2bfu(float x) {
    __hip_bfloat16 b = __float2bfloat16(x);   // RNE
    unsigned short u; __builtin_memcpy(&u, &b, 2); return u;
}
__device__ __forceinline__ float bfu2f(unsigned short u) {
    unsigned int w = ((unsigned int)u) << 16; return __uint_as_float(w);
}
__device__ __forceinline__ f32x4 mfma16(s16x8 a, s16x8 b, f32x4 c) {
    return __builtin_amdgcn_mfma_f32_16x16x32_bf16(
        __builtin_bit_cast(bf16x8, a), __builtin_bit_cast(bf16x8, b), c, 0, 0, 0);
}

// hi/lo split of 8 fp32 (truncation split; residual ~2^-16 rel).
__device__ __forceinline__ void split8v(f32x4 v0, f32x4 v1, s16x8& hi, s16x8& lo)
{
    float x[8] = {v0[0], v0[1], v0[2], v0[3], v1[0], v1[1], v1[2], v1[3]};
    unsigned hw[4], lw[4];
    #pragma unroll
    for (int d = 0; d < 4; ++d) {
        const unsigned u0 = __float_as_uint(x[2*d]);
        const unsigned u1 = __float_as_uint(x[2*d + 1]);
        hw[d] = __builtin_amdgcn_perm(u1, u0, 0x07060302);
        const float l0 = x[2*d]     - __uint_as_float(u0 & 0xFFFF0000u);
        const float l1 = x[2*d + 1] - __uint_as_float(u1 & 0xFFFF0000u);
        lw[d] = __builtin_amdgcn_perm(__float_as_uint(l1), __float_as_uint(l0),
                                      0x07060302);
    }
    hi = __builtin_bit_cast(s16x8, *(unsigned(*)[4])hw);
    lo = __builtin_bit_cast(s16x8, *(unsigned(*)[4])lw);
}

__device__ __forceinline__ void gll16(const void* g, void* l) {
    __builtin_amdgcn_global_load_lds(
        (const __attribute__((address_space(1))) unsigned int*)g,
        (__attribute__((address_space(3))) unsigned int*)l,
        16, 0, 0);
}

// ---------------- K0: dtype detect ----------------
__global__ __launch_bounds__(256) void detect_kernel(const unsigned short* __restrict__ hraw,
                                                     int* __restrict__ flag)
{
    const int tid = threadIdx.x;
    float m = 0.0f;
    for (int i = tid; i < 16384; i += 256) {
        unsigned int w = ((unsigned int)hraw[i]) << 16;
        float v = __uint_as_float(w);
        v = fabsf(v);
        if (!(v == v)) v = 1e30f;
        m = fmaxf(m, v);
    }
    #pragma unroll
    for (int off = 32; off >= 1; off >>= 1)
        m = fmaxf(m, __shfl_down(m, off));
    __shared__ float red[4];
    if ((tid & 63) == 0) red[tid >> 6] = m;
    __syncthreads();
    if (tid == 0) {
        float mm = fmaxf(fmaxf(red[0], red[1]), fmaxf(red[2], red[3]));
        *flag = (mm > 1e4f) ? 1 : 0;
    }
}

// ---------------- KP: W -> Wt[f][k] bf16 hi/lo ----------------
__global__ __launch_bounds__(256) void prep_w_kernel(
    const void* __restrict__ Wv, const int* __restrict__ flagp,
    short* __restrict__ WtHi, short* __restrict__ WtLo)
{
    const int flag = *flagp;
    __shared__ float tile[16][17];
    const int tx = threadIdx.x & 15, ty = threadIdx.x >> 4;
    const int kk = blockIdx.y * 16 + ty;
    const int f  = blockIdx.x * 16 + tx;
    float v;
    if (flag) v = ((const float*)Wv)[kk * FDIM + f];
    else      v = bfu2f(((const unsigned short*)Wv)[kk * FDIM + f]);
    tile[ty][tx] = v;
    __syncthreads();
    const float x = tile[tx][ty];
    const int fo = blockIdx.x * 16 + ty;
    const int ko = blockIdx.y * 16 + tx;
    unsigned short h = f2bfu(x);
    WtHi[fo * FDIM + ko] = (short)h;
    WtLo[fo * FDIM + ko] = (short)f2bfu(x - bfu2f(h));  // exact 0 in bf16 mode
}

// ---------------- KA: Wh = h@W ----------------
// 512 blocks x 512 thr (8 waves; LDS 68K -> 2 blocks/CU, 16 waves/CU).
// Wave w owns cols [w*32, w*32+32). A panel (64x256 hi/lo) in LDS:
// byte = row*512 + ((seg ^ (row&7))*16), seg = k/8; lo at +32K.
// K-loop barrier-free; B via depth-2 register pipeline from global (L2).
__global__ __launch_bounds__(512, 4) void wh_gemm(
    const void* __restrict__ hv,
    const short* __restrict__ WtHi, const short* __restrict__ WtLo,
    const void* __restrict__ av, const int* __restrict__ flagp,
    short* __restrict__ WhTHi, short* __restrict__ WhTLo,
    float* __restrict__ srcv, float* __restrict__ dstv)
{
    __shared__ __align__(16) char smem[69632];  // A hi 32K | A lo 32K | red 4K

    const int flag = *flagp;
    const int blk = blockIdx.x;
    const int bn  = blk >> 3;
    const int i0  = (blk & 7) * 64;
    const size_t r0g = (size_t)blk * 64;
    const int tid = threadIdx.x;
    const int w = tid >> 6, l = tid & 63;
    const int fb = l & 15, g = l >> 4;

    // ---- stage A panel once ----
    if (flag) {
        const int srow = tid >> 3, q = tid & 7;   // 8 threads per row
        const float* gA = (const float*)hv + (r0g + srow) * FDIM;
        #pragma unroll
        for (int i = 0; i < 4; ++i) {
            const int seg = q + 8 * i;
            f32x4 v0 = *(const f32x4*)(gA + seg * 8);
            f32x4 v1 = *(const f32x4*)(gA + seg * 8 + 4);
            s16x8 hi, lo; split8v(v0, v1, hi, lo);
            const int slot = seg ^ (srow & 7);
            *(s16x8*)(smem + srow * 512 + slot * 16) = hi;
            *(s16x8*)(smem + 32768 + srow * 512 + slot * 16) = lo;
        }
    } else {
        const short* hs = (const short*)hv;
        const unsigned wub = (unsigned)(tid & ~63);
        #pragma unroll
        for (int i = 0; i < 4; ++i) {
            const int idx = i * 512 + tid;        // 0..2047
            const int row = idx >> 5, slot = idx & 31;
            const int srcseg = slot ^ (row & 7);
            gll16(hs + (r0g + row) * FDIM + srcseg * 8,
                  smem + (i * 512 + (int)wub) * 16);
        }
    }
    __syncthreads();   // A panel ready (drains vmcnt + lgkm)

    f32x4 acc[4][2];
    #pragma unroll
    for (int rt = 0; rt < 4; ++rt)
        #pragma unroll
        for (int ct = 0; ct < 2; ++ct) acc[rt][ct] = f32x4{0.f,0.f,0.f,0.f};

    const int f0 = w * 32 + fb;
    const int f1 = f0 + 16;
    const short* gH0 = WtHi + f0 * FDIM + g * 8;
    const short* gH1 = WtHi + f1 * FDIM + g * 8;
    const short* gL0 = WtLo + f0 * FDIM + g * 8;
    const short* gL1 = WtLo + f1 * FDIM + g * 8;

    if (flag) {
        // depth-2 pipeline: pb[t%3] holds {bh0, bh1, bl0, bl1} for step t
        s16x8 pb[3][4];
        #pragma unroll
        for (int d = 0; d < 2; ++d) {
            pb[d][0] = *(const s16x8*)(gH0 + d * 32);
            pb[d][1] = *(const s16x8*)(gH1 + d * 32);
            pb[d][2] = *(const s16x8*)(gL0 + d * 32);
            pb[d][3] = *(const s16x8*)(gL1 + d * 32);
        }
        #pragma unroll
        for (int t = 0; t < 8; ++t) {
            const int cur = t % 3;
            if (t + 2 < 8) {
                const int nx = (t + 2) % 3;
                pb[nx][0] = *(const s16x8*)(gH0 + (t + 2) * 32);
                pb[nx][1] = *(const s16x8*)(gH1 + (t + 2) * 32);
                pb[nx][2] = *(const s16x8*)(gL0 + (t + 2) * 32);
                pb[nx][3] = *(const s16x8*)(gL1 + (t + 2) * 32);
            }
            s16x8 ah[4], al[4];
            #pragma unroll
            for (int rt = 0; rt < 4; ++rt) {
                const int row = rt * 16 + fb;
                const int slot = (t * 4 + g) ^ (row & 7);
                ah[rt] = *(const s16x8*)(smem + row * 512 + slot * 16);
                al[rt] = *(const s16x8*)(smem + 32768 + row * 512 + slot * 16);
            }
            __builtin_amdgcn_s_setprio(1);
            #pragma unroll
            for (int rt = 0; rt < 4; ++rt) {
                acc[rt][0] = mfma16(ah[rt], pb[cur][0], acc[rt][0]);
                acc[rt][0] = mfma16(al[rt], pb[cur][0], acc[rt][0]);
                acc[rt][0] = mfma16(ah[rt], pb[cur][2], acc[rt][0]);
                acc[rt][1] = mfma16(ah[rt], pb[cur][1], acc[rt][1]);
                acc[rt][1] = mfma16(al[rt], pb[cur][1], acc[rt][1]);
                acc[rt][1] = mfma16(ah[rt], pb[cur][3], acc[rt][1]);
            }
            __builtin_amdgcn_s_setprio(0);
        }
    } else {
        s16x8 pb[3][2];
        #pragma unroll
        for (int d = 0; d < 2; ++d) {
            pb[d][0] = *(const s16x8*)(gH0 + d * 32);
            pb[d][1] = *(const s16x8*)(gH1 + d * 32);
        }
        #pragma unroll
        for (int t = 0; t < 8; ++t) {
            const int cur = t % 3;
            if (t + 2 < 8) {
                const int nx = (t + 2) % 3;
                pb[nx][0] = *(const s16x8*)(gH0 + (t + 2) * 32);
                pb[nx][1] = *(const s16x8*)(gH1 + (t + 2) * 32);
            }
            s16x8 ah[4];
            #pragma unroll
            for (int rt = 0; rt < 4; ++rt) {
                const int row = rt * 16 + fb;
                const int slot = (t * 4 + g) ^ (row & 7);
                ah[rt] = *(const s16x8*)(smem + row * 512 + slot * 16);
            }
            __builtin_amdgcn_s_setprio(1);
            #pragma unroll
            for (int rt = 0; rt < 4; ++rt) {
                acc[rt][0] = mfma16(ah[rt], pb[cur][0], acc[rt][0]);
                acc[rt][1] = mfma16(ah[rt], pb[cur][1], acc[rt][1]);
            }
            __builtin_amdgcn_s_setprio(0);
        }
    }

    // Write WhT[bn][f][i] hi/lo. D: row = rt*16 + g*4 + r, col = f.
    const size_t wbT = (size_t)bn * FDIM * NODES;
    #pragma unroll
    for (int rt = 0; rt < 4; ++rt) {
        const int orow = i0 + rt * 16 + g * 4;
        #pragma unroll
        for (int ct = 0; ct < 2; ++ct) {
            const int f = w * 32 + ct * 16 + fb;
            s16x4 h4, l4;
            #pragma unroll
            for (int r = 0; r < 4; ++r) {
                float x = acc[rt][ct][r];
                unsigned short hh = f2bfu(x);
                h4[r] = (short)hh;
                l4[r] = (short)f2bfu(x - bfu2f(hh));
            }
            *(s16x4*)(WhTHi + wbT + (size_t)f * NODES + orow) = h4;
            *(s16x4*)(WhTLo + wbT + (size_t)f * NODES + orow) = l4;
        }
    }

    // src/dst reduction (fp32 accumulator path).
    float a1v[2], a2v[2];
    #pragma unroll
    for (int ct = 0; ct < 2; ++ct) {
        const int f = w * 32 + ct * 16 + fb;
        if (flag) {
            a1v[ct] = ((const float*)av)[f];
            a2v[ct] = ((const float*)av)[FDIM + f];
        } else {
            a1v[ct] = bfu2f(((const unsigned short*)av)[f]);
            a2v[ct] = bfu2f(((const unsigned short*)av)[FDIM + f]);
        }
    }
    float* red1 = (float*)(smem + 65536);   // [8][64]
    float* red2 = (float*)(smem + 67584);   // [8][64]
    #pragma unroll
    for (int rt = 0; rt < 4; ++rt) {
        #pragma unroll
        for (int r = 0; r < 4; ++r) {
            float s1 = 0.f, s2 = 0.f;
            #pragma unroll
            for (int ct = 0; ct < 2; ++ct) {
                s1 = fmaf(acc[rt][ct][r], a1v[ct], s1);
                s2 = fmaf(acc[rt][ct][r], a2v[ct], s2);
            }
            #pragma unroll
            for (int off = 1; off <= 8; off <<= 1) {
                s1 += __shfl_xor(s1, off);
                s2 += __shfl_xor(s2, off);
            }
            if (fb == 0) {
                red1[w * 64 + rt * 16 + g * 4 + r] = s1;
                red2[w * 64 + rt * 16 + g * 4 + r] = s2;
            }
        }
    }
    __syncthreads();
    if (tid < 64) {
        float s1 = 0.f, s2 = 0.f;
        #pragma unroll
        for (int ww = 0; ww < 8; ++ww) {
            s1 += red1[ww * 64 + tid];
            s2 += red2[ww * 64 + tid];
        }
        srcv[bn * NODES + i0 + tid] = s1;
        dstv[bn * NODES + i0 + tid] = s2;
    }
}

// ---------------- KB: fused softmax + att@Wh + elu ----------------
// 512 blocks (XCD-swizzled) x 512 thr (8 waves; LDS 64K -> 2 blocks/CU).
// Wave w owns cols [w*32, w*32+32). P (pre-normalized bf16) in LDS;
// K-loop barrier-free, B via depth-2 register pipeline from global (L2).
__global__ __launch_bounds__(512, 4) void pv_gemm(
    const short* __restrict__ WhTHi, const short* __restrict__ WhTLo,
    const float* __restrict__ srcv, const float* __restrict__ dstv,
    const int* __restrict__ adj, const int* __restrict__ flagp,
    void* __restrict__ out)
{
    __shared__ __align__(16) char smem[65536];   // Ps [64 rows][64 slots x16B]

    const int flag = *flagp;
    const int b0 = blockIdx.x;
    const int blk = (b0 & 7) * 64 + (b0 >> 3);   // bijective: 512 % 8 == 0
    const int bn  = blk >> 3;
    const int i0  = (blk & 7) * 64;
    const int tid = threadIdx.x;
    const int w = tid >> 6, l = tid & 63;

    const short* bhig = WhTHi + (size_t)bn * FDIM * NODES;
    const short* blog = WhTLo + (size_t)bn * FDIM * NODES;

    // ---- softmax: wave w -> rows w*8..w*8+8; lane l covers j = 8l..8l+8 ----
    {
        const float* drow = dstv + bn * NODES;
        const int j = l * 8;
        for (int rr = 0; rr < 8; ++rr) {
            const int r = w * 8 + rr;
            const int* adjrow = adj + (size_t)(i0 + r) * NODES;
            const float srow = srcv[bn * NODES + i0 + r];
            const i32x4 q0 = *(const i32x4*)(adjrow + j);
            const i32x4 q1 = *(const i32x4*)(adjrow + j + 4);
            const f32x4 d0 = *(const f32x4*)(drow + j);
            const f32x4 d1 = *(const f32x4*)(drow + j + 4);
            float e[8];
            #pragma unroll
            for (int k = 0; k < 4; ++k) {
                float ev = srow + d0[k];
                ev = (ev > 0.f) ? ev : ALPHA * ev;
                e[k] = (q0[k] > 0) ? ev : MASK_VAL;
                float ew = srow + d1[k];
                ew = (ew > 0.f) ? ew : ALPHA * ew;
                e[4 + k] = (q1[k] > 0) ? ew : MASK_VAL;
            }
            float m = e[0];
            #pragma unroll
            for (int k = 1; k < 8; ++k) m = fmaxf(m, e[k]);
            #pragma unroll
            for (int off = 1; off <= 32; off <<= 1) m = fmaxf(m, __shfl_xor(m, off));
            float p[8], s = 0.f;
            #pragma unroll
            for (int k = 0; k < 8; ++k) {
                p[k] = __expf(e[k] - m);   // masked -> 0; all-masked row -> 1
                s += p[k];
            }
            #pragma unroll
            for (int off = 1; off <= 32; off <<= 1) s += __shfl_xor(s, off);
            const float isum = 1.0f / s;
            s16x8 ph;
            #pragma unroll
            for (int k = 0; k < 8; ++k) ph[k] = (short)f2bfu(p[k] * isum);
            // chunk l stored at slot l ^ (r&7)
            *(s16x8*)(smem + r * 1024 + ((l ^ (r & 7)) * 16)) = ph;
        }
    }
    __syncthreads();   // P ready for all waves

    // ---- PV GEMM: 16 K-steps, barrier-free, depth-2 reg pipeline ----
    const int fb = l & 15, g = l >> 4;
    const int f0 = w * 32 + fb;
    const int f1 = f0 + 16;
    const short* gH0 = bhig + (size_t)f0 * NODES + g * 8;
    const short* gH1 = bhig + (size_t)f1 * NODES + g * 8;
    const short* gL0 = blog + (size_t)f0 * NODES + g * 8;
    const short* gL1 = blog + (size_t)f1 * NODES + g * 8;

    f32x4 acc[4][2];
    #pragma unroll
    for (int rt = 0; rt < 4; ++rt)
        #pragma unroll
        for (int ct = 0; ct < 2; ++ct) acc[rt][ct] = f32x4{0.f,0.f,0.f,0.f};

    s16x8 pb[3][4];
    #pragma unroll
    for (int d = 0; d < 2; ++d) {
        pb[d][0] = *(const s16x8*)(gH0 + d * 32);
        pb[d][1] = *(const s16x8*)(gH1 + d * 32);
        pb[d][2] = *(const s16x8*)(gL0 + d * 32);
        pb[d][3] = *(const s16x8*)(gL1 + d * 32);
    }
    #pragma unroll
    for (int t = 0; t < 16; ++t) {
        const int cur = t % 3;
        if (t + 2 < 16) {
            const int nx = (t + 2) % 3;
            pb[nx][0] = *(const s16x8*)(gH0 + (t + 2) * 32);
            pb[nx][1] = *(const s16x8*)(gH1 + (t + 2) * 32);
            pb[nx][2] = *(const s16x8*)(gL0 + (t + 2) * 32);
            pb[nx][3] = *(const s16x8*)(gL1 + (t + 2) * 32);
        }
        s16x8 af[4];
        #pragma unroll
        for (int rt = 0; rt < 4; ++rt) {
            const int row = rt * 16 + fb;
            const unsigned seg = (unsigned)(t * 4 + g) ^ (unsigned)(row & 7);
            af[rt] = *(const s16x8*)(smem + (unsigned)(row * 1024) + seg * 16);
        }
        __builtin_amdgcn_s_setprio(1);
        #pragma unroll
        for (int rt = 0; rt < 4; ++rt) {
            acc[rt][0] = mfma16(af[rt], pb[cur][0], acc[rt][0]);
            acc[rt][0] = mfma16(af[rt], pb[cur][2], acc[rt][0]);
            acc[rt][1] = mfma16(af[rt], pb[cur][1], acc[rt][1]);
            acc[rt][1] = mfma16(af[rt], pb[cur][3], acc[rt][1]);
        }
        __builtin_amdgcn_s_setprio(0);
    }

    // epilogue: elu, store (P pre-normalized). D row = rt*16 + g*4 + r.
    #pragma unroll
    for (int rt = 0; rt < 4; ++rt) {
        #pragma unroll
        for (int ct = 0; ct < 2; ++ct) {
            const int f = w * 32 + ct * 16 + fb;
            #pragma unroll
            for (int r = 0; r < 4; ++r) {
                float v = acc[rt][ct][r];
                v = (v > 0.f) ? v : expm1f(v);
                const size_t o = ((size_t)bn * NODES + i0 + rt * 16 + g * 4 + r) * FDIM + f;
                if (flag) ((float*)out)[o] = v;
                else      ((unsigned short*)out)[o] = f2bfu(v);
            }
        }
    }
}

extern "C" void kernel_launch(void* const* d_in, const int* in_sizes, int n_in,
                              void* d_out, int out_size, void* d_ws, size_t ws_size,
                              hipStream_t stream)
{
    const void* h   = d_in[0];
    const int*  adj = (const int*)d_in[1];
    const void* W   = d_in[2];
    const void* a   = d_in[3];

    // ws layout: flag 256B | src 128K | dst 128K | WtHi 128K | WtLo 128K
    //            | WhTHi 16.78M | WhTLo 16.78M   (~34.1 MB total)
    int*   flag  = (int*)d_ws;
    float* srcv  = (float*)d_ws + 64;
    float* dstv  = srcv + BN * NODES;
    short* WtHi  = (short*)(dstv + BN * NODES);
    short* WtLo  = WtHi + FDIM * FDIM;
    short* WhTHi = WtLo + FDIM * FDIM;
    short* WhTLo = WhTHi + (size_t)BN * FDIM * NODES;

    detect_kernel<<<1, 256, 0, stream>>>((const unsigned short*)h, flag);
    prep_w_kernel<<<dim3(16, 16), 256, 0, stream>>>(W, flag, WtHi, WtLo);
    wh_gemm<<<512, 512, 0, stream>>>(h, WtHi, WtLo, a, flag,
                                     WhTHi, WhTLo, srcv, dstv);
    pv_gemm<<<512, 512, 0, stream>>>(WhTHi, WhTLo, srcv, dstv, adj, flag, d_out);
}